// Round 6
// baseline (71.757 us; speedup 1.0000x reference)
//
#include <hip/hip_runtime.h>
#include <math.h>

// Problem constants
#define BATCH   8
#define LDIM    20
#define PIX     25600   // 160*160
#define PIX4    6400    // PIX/4 (float4 elements per image)
#define NLPAIRS 400     // N*L
#define NLR     800     // N*L*2

// Projection split
#define NLG     2                   // nl-pairs per block -> 4 basis rows (acc=32 VGPR, no spill)
#define PROWS   (NLG * 2)           // 4
#define KSPLIT  25                  // pixel-dimension split
#define SLICE   (PIX4 / KSPLIT)     // 256 float4
#define PTHR    256                 // threads per proj block (4 waves)
#define PITER   (SLICE / PTHR)      // 1 iteration

// Reconstruction split
#define RPIX    64                  // pixels per recon block
#define RKS     8                   // k-slices (one per wave, 512 threads)
#define RKLEN   (NLR / RKS)         // 100 k per wave

// ---------------------------------------------------------------------------
// Kernel A: split-K projection.
// grid = (200 row-groups, 25 K-slices) = 5000 blocks x 4 waves = 20000 waves.
// Each block: 4 basis rows over a 256-float4 pixel slice, 1 iter/thread.
// Butterfly-reduce 32 partials, write part[slice][800][8].
// ---------------------------------------------------------------------------
__global__ __launch_bounds__(PTHR, 2) void proj_kernel(
    const float* __restrict__ x,       // [8][25600]
    const float* __restrict__ basis,   // [800][25600]
    float* __restrict__ part)          // [KSPLIT][800][8]
{
    const int tid   = threadIdx.x;
    const int rbase = blockIdx.x * PROWS;            // first basis row (4 rows)
    const int kbase = blockIdx.y * SLICE;            // float4 offset of slice

    const float4* __restrict__ x4 = (const float4*)x;

    float acc[PROWS][BATCH];
    #pragma unroll
    for (int r = 0; r < PROWS; ++r)
        #pragma unroll
        for (int b = 0; b < BATCH; ++b) acc[r][b] = 0.0f;

    #pragma unroll
    for (int it = 0; it < PITER; ++it) {
        const int i = kbase + it * PTHR + tid;

        float4 bv[PROWS];
        #pragma unroll
        for (int r = 0; r < PROWS; ++r)
            bv[r] = ((const float4*)(basis + (size_t)(rbase + r) * PIX))[i];

        #pragma unroll
        for (int b = 0; b < BATCH; ++b) {
            float4 xv = x4[(size_t)b * PIX4 + i];
            #pragma unroll
            for (int r = 0; r < PROWS; ++r) {
                acc[r][b] = fmaf(bv[r].x, xv.x, acc[r][b]);
                acc[r][b] = fmaf(bv[r].y, xv.y, acc[r][b]);
                acc[r][b] = fmaf(bv[r].z, xv.z, acc[r][b]);
                acc[r][b] = fmaf(bv[r].w, xv.w, acc[r][b]);
            }
        }
    }

    // Intra-wave butterfly reduction of all 32 partials to lane 0
    #pragma unroll
    for (int r = 0; r < PROWS; ++r)
        #pragma unroll
        for (int b = 0; b < BATCH; ++b)
            #pragma unroll
            for (int off = 32; off > 0; off >>= 1)
                acc[r][b] += __shfl_down(acc[r][b], off);

    __shared__ float red[4][PROWS * BATCH];
    const int wave = tid >> 6;
    const int lane = tid & 63;
    if (lane == 0) {
        #pragma unroll
        for (int r = 0; r < PROWS; ++r)
            #pragma unroll
            for (int b = 0; b < BATCH; ++b)
                red[wave][r * BATCH + b] = acc[r][b];
    }
    __syncthreads();

    if (tid < PROWS * BATCH) {
        part[(size_t)blockIdx.y * NLR * BATCH + rbase * BATCH + tid] =
            red[0][tid] + red[1][tid] + red[2][tid] + red[3][tid];
    }
}

// ---------------------------------------------------------------------------
// Kernel B: partial-sum + rotation, computed ONCE.
// grid = 25 blocks * 256 = 6400 threads = one per (nlr, b).
// ---------------------------------------------------------------------------
__global__ __launch_bounds__(256) void rotate_kernel(
    const float* __restrict__ part,    // [KSPLIT][800][8]
    const float* __restrict__ angles,  // [8]
    float* __restrict__ rot)           // [800][8]
{
    const int idx = blockIdx.x * 256 + threadIdx.x;   // 0..6399
    const int nlr = idx >> 3;
    const int b   = idx & 7;

    float self = 0.0f, other = 0.0f;
    #pragma unroll
    for (int s = 0; s < KSPLIT; ++s) {
        self  += part[((size_t)s * NLR + nlr) * BATCH + b];
        other += part[((size_t)s * NLR + (nlr ^ 1)) * BATCH + b];
    }
    const int l = (nlr >> 1) % LDIM;
    float ca, sa;
    __sincosf(angles[b] * (float)l, &sa, &ca);
    // a = c0*ca + c1*sa ; b = c1*ca - c0*sa
    rot[idx] = (nlr & 1) == 0 ? fmaf(self, ca, other * sa)
                              : fmaf(self, ca, -other * sa);
}

// ---------------------------------------------------------------------------
// Kernel C: reconstruction (unchanged control from round 4).
// grid = 400 blocks of 512 threads (8 waves). Each wave owns a 100-k slice
// over 64 pixels; LDS tree-reduce across waves; direct coalesced stores.
// ---------------------------------------------------------------------------
__global__ __launch_bounds__(512) void recon_kernel(
    const float* __restrict__ basis,   // [800][25600]
    const float* __restrict__ rot,     // [800][8]
    float* __restrict__ out)           // [8][25600]
{
    __shared__ float rl[NLR * BATCH];            // 25.6 KB rotated coeffs
    __shared__ float red[RKS - 1][BATCH][RPIX];  // 14.3 KB, lane-consecutive

    const int tid = threadIdx.x;

    // Stage rotated coeffs (simple L2 copy, broadcast-read later)
    for (int idx = tid; idx < NLR * BATCH; idx += 512)
        rl[idx] = rot[idx];
    __syncthreads();

    const int lane = tid & 63;
    const int ks   = tid >> 6;                 // wave = k-slice
    const int pix  = blockIdx.x * RPIX + lane;

    float acc[BATCH];
    #pragma unroll
    for (int b = 0; b < BATCH; ++b) acc[b] = 0.0f;

    const float* __restrict__ bp = basis + (size_t)(ks * RKLEN) * PIX + pix;
    const float* __restrict__ rp = &rl[(ks * RKLEN) * BATCH];

    #pragma unroll 10
    for (int k = 0; k < RKLEN; ++k) {
        float bv = bp[(size_t)k * PIX];
        float4 v0 = *(const float4*)&rp[k * BATCH];
        float4 v1 = *(const float4*)&rp[k * BATCH + 4];
        acc[0] = fmaf(bv, v0.x, acc[0]);
        acc[1] = fmaf(bv, v0.y, acc[1]);
        acc[2] = fmaf(bv, v0.z, acc[2]);
        acc[3] = fmaf(bv, v0.w, acc[3]);
        acc[4] = fmaf(bv, v1.x, acc[4]);
        acc[5] = fmaf(bv, v1.y, acc[5]);
        acc[6] = fmaf(bv, v1.z, acc[6]);
        acc[7] = fmaf(bv, v1.w, acc[7]);
    }

    if (ks > 0) {
        #pragma unroll
        for (int b = 0; b < BATCH; ++b)
            red[ks - 1][b][lane] = acc[b];   // consecutive lanes -> consecutive addrs
    }
    __syncthreads();

    if (ks == 0) {
        #pragma unroll
        for (int w = 0; w < RKS - 1; ++w)
            #pragma unroll
            for (int b = 0; b < BATCH; ++b)
                acc[b] += red[w][b][lane];
        #pragma unroll
        for (int b = 0; b < BATCH; ++b)
            out[(size_t)b * PIX + pix] = acc[b];
    }
}

extern "C" void kernel_launch(void* const* d_in, const int* in_sizes, int n_in,
                              void* d_out, int out_size, void* d_ws, size_t ws_size,
                              hipStream_t stream) {
    (void)in_sizes; (void)n_in; (void)ws_size; (void)out_size;

    const float* x      = (const float*)d_in[0];   // [8][1][160][160]
    const float* basis  = (const float*)d_in[1];   // [20][20][2][160][160]
    const float* angles = (const float*)d_in[2];   // [8]
    float* out  = (float*)d_out;                   // [8][1][160][160]
    float* part = (float*)d_ws;                    // [25][800][8] = 640 KB
    float* rot  = part + (size_t)KSPLIT * NLR * BATCH;  // [800][8] = 25.6 KB

    proj_kernel<<<dim3(NLPAIRS / NLG, KSPLIT), dim3(PTHR), 0, stream>>>(x, basis, part);
    rotate_kernel<<<dim3(NLR * BATCH / 256), dim3(256), 0, stream>>>(part, angles, rot);
    recon_kernel<<<dim3(PIX / RPIX), dim3(512), 0, stream>>>(basis, rot, out);
}

// Round 7
// 41.974 us; speedup vs baseline: 1.7096x; 1.7096x over previous
//
#include <hip/hip_runtime.h>
#include <math.h>

// Problem constants
#define BATCH   8
#define LDIM    20
#define PIX     25600   // 160*160
#define PIX4    6400    // PIX/4 (float4 elements per image)
#define NLPAIRS 400     // N*L
#define NLR     800     // N*L*2

// Projection split
#define KSPLIT  20                  // pixel-dimension split
#define SLICE   (PIX4 / KSPLIT)     // 320 float4 per slice
#define WITER   (SLICE / 64)        // 5 iterations per wave (64 lanes)
#define BROWS   8                   // rows per block = 4 waves * 2 rows

// Reconstruction split
#define RPIX    64                  // pixels per recon block
#define RKS     8                   // k-slices (one per wave, 512 threads)
#define RKLEN   (NLR / RKS)         // 100 k per wave

// ---------------------------------------------------------------------------
// Kernel A: split-K projection, wave-per-row-pair.
// grid = (100 row-groups, 20 K-slices) = 2000 blocks x 4 waves = 8000 waves.
// Each wave owns 2 basis rows over a 320-float4 slice (5 iters/lane).
// 16 accs/thread (~50 VGPR), butterfly reduce within the wave, lane 0 writes
// part[slice][row][8]. NO __syncthreads, NO LDS, NO cross-wave traffic.
// ---------------------------------------------------------------------------
__global__ __launch_bounds__(256) void proj_kernel(
    const float* __restrict__ x,       // [8][25600]
    const float* __restrict__ basis,   // [800][25600]
    float* __restrict__ part)          // [KSPLIT][800][8]
{
    const int tid   = threadIdx.x;
    const int lane  = tid & 63;
    const int wv    = tid >> 6;                      // 0..3
    const int r0    = blockIdx.x * BROWS + wv * 2;   // this wave's first row
    const int kbase = blockIdx.y * SLICE;            // float4 offset of slice

    const float4* __restrict__ b0 = (const float4*)(basis + (size_t)r0 * PIX);
    const float4* __restrict__ b1 = (const float4*)(basis + (size_t)(r0 + 1) * PIX);
    const float4* __restrict__ x4 = (const float4*)x;

    float acc0[BATCH], acc1[BATCH];
    #pragma unroll
    for (int b = 0; b < BATCH; ++b) { acc0[b] = 0.0f; acc1[b] = 0.0f; }

    #pragma unroll
    for (int it = 0; it < WITER; ++it) {
        const int i = kbase + it * 64 + lane;
        float4 v0 = b0[i];
        float4 v1 = b1[i];
        #pragma unroll
        for (int b = 0; b < BATCH; ++b) {
            float4 xv = x4[(size_t)b * PIX4 + i];
            acc0[b] = fmaf(v0.x, xv.x, acc0[b]);
            acc0[b] = fmaf(v0.y, xv.y, acc0[b]);
            acc0[b] = fmaf(v0.z, xv.z, acc0[b]);
            acc0[b] = fmaf(v0.w, xv.w, acc0[b]);
            acc1[b] = fmaf(v1.x, xv.x, acc1[b]);
            acc1[b] = fmaf(v1.y, xv.y, acc1[b]);
            acc1[b] = fmaf(v1.z, xv.z, acc1[b]);
            acc1[b] = fmaf(v1.w, xv.w, acc1[b]);
        }
    }

    // Intra-wave butterfly reduction (16 values -> lane 0)
    #pragma unroll
    for (int b = 0; b < BATCH; ++b) {
        #pragma unroll
        for (int off = 32; off > 0; off >>= 1) {
            acc0[b] += __shfl_down(acc0[b], off);
            acc1[b] += __shfl_down(acc1[b], off);
        }
    }

    if (lane == 0) {
        float* __restrict__ dst =
            part + ((size_t)blockIdx.y * NLR + r0) * BATCH;
        #pragma unroll
        for (int b = 0; b < BATCH; ++b) {
            dst[b]         = acc0[b];
            dst[BATCH + b] = acc1[b];
        }
    }
}

// ---------------------------------------------------------------------------
// Kernel B: partial-sum + rotation, computed ONCE.
// grid = 25 blocks * 256 = 6400 threads = one per (nlr, b).
// ---------------------------------------------------------------------------
__global__ __launch_bounds__(256) void rotate_kernel(
    const float* __restrict__ part,    // [KSPLIT][800][8]
    const float* __restrict__ angles,  // [8]
    float* __restrict__ rot)           // [800][8]
{
    const int idx = blockIdx.x * 256 + threadIdx.x;   // 0..6399
    const int nlr = idx >> 3;
    const int b   = idx & 7;

    float self = 0.0f, other = 0.0f;
    #pragma unroll
    for (int s = 0; s < KSPLIT; ++s) {
        self  += part[((size_t)s * NLR + nlr) * BATCH + b];
        other += part[((size_t)s * NLR + (nlr ^ 1)) * BATCH + b];
    }
    const int l = (nlr >> 1) % LDIM;
    float ca, sa;
    __sincosf(angles[b] * (float)l, &sa, &ca);
    // a = c0*ca + c1*sa ; b = c1*ca - c0*sa
    rot[idx] = (nlr & 1) == 0 ? fmaf(self, ca, other * sa)
                              : fmaf(self, ca, -other * sa);
}

// ---------------------------------------------------------------------------
// Kernel C: reconstruction (unchanged control from round 4).
// grid = 400 blocks of 512 threads (8 waves). Each wave owns a 100-k slice
// over 64 pixels; LDS tree-reduce across waves; direct coalesced stores.
// ---------------------------------------------------------------------------
__global__ __launch_bounds__(512) void recon_kernel(
    const float* __restrict__ basis,   // [800][25600]
    const float* __restrict__ rot,     // [800][8]
    float* __restrict__ out)           // [8][25600]
{
    __shared__ float rl[NLR * BATCH];            // 25.6 KB rotated coeffs
    __shared__ float red[RKS - 1][BATCH][RPIX];  // 14.3 KB, lane-consecutive

    const int tid = threadIdx.x;

    // Stage rotated coeffs (simple L2 copy, broadcast-read later)
    for (int idx = tid; idx < NLR * BATCH; idx += 512)
        rl[idx] = rot[idx];
    __syncthreads();

    const int lane = tid & 63;
    const int ks   = tid >> 6;                 // wave = k-slice
    const int pix  = blockIdx.x * RPIX + lane;

    float acc[BATCH];
    #pragma unroll
    for (int b = 0; b < BATCH; ++b) acc[b] = 0.0f;

    const float* __restrict__ bp = basis + (size_t)(ks * RKLEN) * PIX + pix;
    const float* __restrict__ rp = &rl[(ks * RKLEN) * BATCH];

    #pragma unroll 10
    for (int k = 0; k < RKLEN; ++k) {
        float bv = bp[(size_t)k * PIX];
        float4 v0 = *(const float4*)&rp[k * BATCH];
        float4 v1 = *(const float4*)&rp[k * BATCH + 4];
        acc[0] = fmaf(bv, v0.x, acc[0]);
        acc[1] = fmaf(bv, v0.y, acc[1]);
        acc[2] = fmaf(bv, v0.z, acc[2]);
        acc[3] = fmaf(bv, v0.w, acc[3]);
        acc[4] = fmaf(bv, v1.x, acc[4]);
        acc[5] = fmaf(bv, v1.y, acc[5]);
        acc[6] = fmaf(bv, v1.z, acc[6]);
        acc[7] = fmaf(bv, v1.w, acc[7]);
    }

    if (ks > 0) {
        #pragma unroll
        for (int b = 0; b < BATCH; ++b)
            red[ks - 1][b][lane] = acc[b];   // consecutive lanes -> consecutive addrs
    }
    __syncthreads();

    if (ks == 0) {
        #pragma unroll
        for (int w = 0; w < RKS - 1; ++w)
            #pragma unroll
            for (int b = 0; b < BATCH; ++b)
                acc[b] += red[w][b][lane];
        #pragma unroll
        for (int b = 0; b < BATCH; ++b)
            out[(size_t)b * PIX + pix] = acc[b];
    }
}

extern "C" void kernel_launch(void* const* d_in, const int* in_sizes, int n_in,
                              void* d_out, int out_size, void* d_ws, size_t ws_size,
                              hipStream_t stream) {
    (void)in_sizes; (void)n_in; (void)ws_size; (void)out_size;

    const float* x      = (const float*)d_in[0];   // [8][1][160][160]
    const float* basis  = (const float*)d_in[1];   // [20][20][2][160][160]
    const float* angles = (const float*)d_in[2];   // [8]
    float* out  = (float*)d_out;                   // [8][1][160][160]
    float* part = (float*)d_ws;                    // [20][800][8] = 512 KB
    float* rot  = part + (size_t)KSPLIT * NLR * BATCH;  // [800][8] = 25.6 KB

    proj_kernel<<<dim3(NLR / BROWS, KSPLIT), dim3(256), 0, stream>>>(x, basis, part);
    rotate_kernel<<<dim3(NLR * BATCH / 256), dim3(256), 0, stream>>>(part, angles, rot);
    recon_kernel<<<dim3(PIX / RPIX), dim3(512), 0, stream>>>(basis, rot, out);
}